// Round 3
// baseline (212.552 us; speedup 1.0000x reference)
//
#include <hip/hip_runtime.h>
#include <math.h>

#define BN 8192
#define CN 1000
#define DN 128
#define INVT (1.0f/0.3f)

typedef __bf16 bf16x8 __attribute__((ext_vector_type(8)));
typedef float  f32x4  __attribute__((ext_vector_type(4)));

// ws layout in floats
#define F_FEATN  0          // 8192*128
#define F_MEANSN 1048576    // 1000*128
#define F_XX     1176576    // 8192
#define F_YY     1184768    // 1000
#define F_DIAG   1185768    // 8192  ||bf16(f_i)||^2
#define F_FEATB  1193960    // 8192*128 bf16 = 524288 floats
#define F_MEANSB 1718248    // 1024*128 bf16
#define F_CEROW  1783784    // 8192
#define F_MROW   1791976    // 8192
#define F_PM     1800168    // 16*8192 logsumexp partial max
#define F_PL     1931240    // 16*8192 partial sum
#define F_PLAB   2062312    // 16*8192 label-logit partial
#define F_BOT    2193384    // 8192  -- zeroed region start
#define F_POS    2201576    // 8192
#define F_CNT    2209768    // 1000 ints

// -------- row L2-normalize; also emits bf16 copy + diag = ||bf16 row||^2 --------
__global__ void norm_rows(const float* __restrict__ src, float* __restrict__ dst,
                          float* __restrict__ sq, __bf16* __restrict__ dstb,
                          float* __restrict__ diag, int nrows, int raw_sq) {
    int row = blockIdx.x * 4 + (threadIdx.x >> 6);
    if (row >= nrows) return;
    int lane = threadIdx.x & 63;
    float f0 = src[row * DN + lane];
    float f1 = src[row * DN + 64 + lane];
    float ss = f0 * f0 + f1 * f1;
    #pragma unroll
    for (int o = 32; o > 0; o >>= 1) ss += __shfl_xor(ss, o);
    float inv = 1.0f / fmaxf(sqrtf(ss), 1e-12f);
    float n0 = f0 * inv, n1 = f1 * inv;
    dst[row * DN + lane] = n0;
    dst[row * DN + 64 + lane] = n1;
    if (dstb) {
        __bf16 b0 = (__bf16)n0, b1 = (__bf16)n1;
        dstb[row * DN + lane] = b0;
        dstb[row * DN + 64 + lane] = b1;
        float fb0 = (float)b0, fb1 = (float)b1;
        float sb = fb0 * fb0 + fb1 * fb1;
        #pragma unroll
        for (int o = 32; o > 0; o >>= 1) sb += __shfl_xor(sb, o);
        if (lane == 0) diag[row] = sb;
    }
    if (lane == 0) sq[row] = raw_sq ? ss : ss * inv * inv;
}

__global__ void to_bf16_pad(const float* __restrict__ src, __bf16* __restrict__ dst,
                            int nrows_src) {
    int idx = blockIdx.x * 256 + threadIdx.x;     // 1024*128 total
    int row = idx >> 7;
    dst[idx] = (__bf16)((row < nrows_src) ? src[idx] : 0.f);
}

__global__ void hist_kernel(const int* __restrict__ labels, int* __restrict__ counts) {
    int i = blockIdx.x * 256 + threadIdx.x;
    atomicAdd(&counts[labels[i]], 1);
}

// stage a 128x128 bf16 tile into LDS as XOR-swizzled 16B chunks
__device__ __forceinline__ void stage128(uint4* sT, const uint4* __restrict__ src,
                                         int row0, int tid) {
    #pragma unroll
    for (int s = 0; s < 8; s++) {
        int c = tid + s * 256;
        int r = c >> 4, ch = c & 15;
        sT[r * 16 + (ch ^ (r & 7))] = src[(size_t)(row0 + r) * 16 + ch];
    }
}

// -------- nsd + fused CE partials: 128x128 tile; writes nsd to out and
// per-(row, strip, col-half) online-softmax partials (m, l, labv) --------
__global__ __launch_bounds__(256, 2) void nsd_kernel(const __bf16* __restrict__ featb,
        const __bf16* __restrict__ meansb, const float* __restrict__ xx,
        const float* __restrict__ yy, const int* __restrict__ labels,
        float* __restrict__ out, float* __restrict__ pm, float* __restrict__ pl,
        float* __restrict__ plab) {
    __shared__ uint4 sA[2048];
    __shared__ uint4 sB[2048];
    int tid = threadIdx.x;
    int i0 = blockIdx.y * 128, j0 = blockIdx.x * 128;
    stage128(sA, (const uint4*)featb, i0, tid);
    stage128(sB, (const uint4*)meansb, j0, tid);
    __syncthreads();
    int lane = tid & 63, w = tid >> 6;
    int wrow = (w >> 1) * 64, wcol = (w & 1) * 64;
    int q = lane >> 4, l15 = lane & 15;
    int ibase = i0 + wrow + q * 4;

    f32x4 acc[4][4];
    #pragma unroll
    for (int ii = 0; ii < 4; ii++)
        #pragma unroll
        for (int jj = 0; jj < 4; jj++) acc[ii][jj] = (f32x4){0.f, 0.f, 0.f, 0.f};
    #pragma unroll
    for (int kk = 0; kk < 4; kk++) {
        bf16x8 af[4], bfv[4];
        #pragma unroll
        for (int ii = 0; ii < 4; ii++) {
            int r = wrow + ii * 16 + l15;
            af[ii] = *(const bf16x8*)&sA[r * 16 + ((kk * 4 + q) ^ (r & 7))];
        }
        #pragma unroll
        for (int jj = 0; jj < 4; jj++) {
            int r = wcol + jj * 16 + l15;
            bfv[jj] = *(const bf16x8*)&sB[r * 16 + ((kk * 4 + q) ^ (r & 7))];
        }
        #pragma unroll
        for (int ii = 0; ii < 4; ii++)
            #pragma unroll
            for (int jj = 0; jj < 4; jj++)
                acc[ii][jj] = __builtin_amdgcn_mfma_f32_16x16x32_bf16(
                    af[ii], bfv[jj], acc[ii][jj], 0, 0, 0);
    }
    int jg[4]; float yv[4];
    #pragma unroll
    for (int jj = 0; jj < 4; jj++) {
        jg[jj] = j0 + wcol + jj * 16 + l15;
        yv[jj] = (jg[jj] < CN) ? yy[jg[jj]] : 0.f;
    }
    int pslot = (blockIdx.x * 2 + (w & 1)) * BN;   // strip x col-half partial slot
    #pragma unroll
    for (int ii = 0; ii < 4; ii++) {
        int rbase = ibase + ii * 16;
        float4 xv = ((const float4*)xx)[rbase >> 2];
        int4 lv = ((const int4*)labels)[rbase >> 2];
        float xa[4] = {xv.x, xv.y, xv.z, xv.w};
        int la[4] = {lv.x, lv.y, lv.z, lv.w};
        #pragma unroll
        for (int r4 = 0; r4 < 4; r4++) {
            int ig = rbase + r4;
            float m = -INFINITY, labc = -INFINITY;
            float lgt[4];
            #pragma unroll
            for (int jj = 0; jj < 4; jj++) {
                float v = -0.5f * (xa[r4] - 2.f * acc[ii][jj][r4] + yv[jj]);
                bool ok = (jg[jj] < CN);
                if (ok) out[(size_t)ig * CN + jg[jj]] = v;
                bool isl = ok && (jg[jj] == la[r4]);
                float l = isl ? 1.5f * v : v;
                if (!ok) l = -INFINITY;
                lgt[jj] = l;
                m = fmaxf(m, l);
                labc = isl ? l : labc;
            }
            float s = 0.f;
            #pragma unroll
            for (int jj = 0; jj < 4; jj++) s += __expf(lgt[jj] - m);
            // merge across the 16 col-lanes
            #pragma unroll
            for (int o = 8; o > 0; o >>= 1) {
                float mo = __shfl_xor(m, o), so = __shfl_xor(s, o);
                float M = fmaxf(m, mo);
                s = s * __expf(m - M) + so * __expf(mo - M);
                m = M;
                labc = fmaxf(labc, __shfl_xor(labc, o));
            }
            if (l15 == 0) {
                pm[pslot + ig] = m;
                pl[pslot + ig] = s;
                plab[pslot + ig] = labc;
            }
        }
    }
}

// merge 16 partials per row -> ce_row
__global__ void ce_merge(const float* __restrict__ pm, const float* __restrict__ pl,
                         const float* __restrict__ plab, float* __restrict__ ce_row) {
    int row = blockIdx.x * 256 + threadIdx.x;
    float M = -INFINITY;
    #pragma unroll
    for (int k = 0; k < 16; k++) M = fmaxf(M, pm[k * BN + row]);
    float S = 0.f; float lv = -INFINITY;
    #pragma unroll
    for (int k = 0; k < 16; k++) {
        S += pl[k * BN + row] * __expf(pm[k * BN + row] - M);
        lv = fmaxf(lv, plab[k * BN + row]);
    }
    ce_row[row] = (M + logf(S)) - lv;
}

__global__ void margin_kernel(const float* __restrict__ featn, const float* __restrict__ meansn,
                              const int* __restrict__ labels, float* __restrict__ m_row) {
    int row = blockIdx.x * 4 + (threadIdx.x >> 6);
    int lane = threadIdx.x & 63;
    int lab = labels[row];
    float d0 = featn[row * DN + lane] - meansn[lab * DN + lane];
    float d1 = featn[row * DN + 64 + lane] - meansn[lab * DN + 64 + lane];
    float ss = d0 * d0 + d1 * d1;
    #pragma unroll
    for (int o = 32; o > 0; o >>= 1) ss += __shfl_xor(ss, o);
    if (lane == 0) m_row[row] = ss;
}

// -------- SCL core: 64-row i-tile, A-frags in registers, B double-buffered
// through registers into 32KB LDS. Branchless epilogue: bs includes the
// diagonal (subtracted in final_kernel via diag[]), ps accumulates raw acc. --------
__global__ __launch_bounds__(256) void scl_kernel(const __bf16* __restrict__ featb,
        const int* __restrict__ labels, float* __restrict__ bottom, float* __restrict__ pos) {
    __shared__ uint4 sB[2048];
    int tid = threadIdx.x;
    int i0 = blockIdx.y * 64;
    int jstrip = blockIdx.x;   // 0..3, each covers 2048 cols = 16 tiles
    const uint4* fv = (const uint4*)featb;
    int lane = tid & 63, w = tid >> 6;
    int wrow = (w >> 1) * 32, wcol = (w & 1) * 64;
    int q = lane >> 4, l15 = lane & 15;

    // A fragments: 2 row-blocks x 4 k-chunks, held in registers for all tiles
    bf16x8 af[2][4];
    #pragma unroll
    for (int ii = 0; ii < 2; ii++) {
        size_t r = (size_t)(i0 + wrow + ii * 16 + l15) * 16;
        #pragma unroll
        for (int kk = 0; kk < 4; kk++)
            af[ii][kk] = *(const bf16x8*)&fv[r + kk * 4 + q];
    }
    int ibase = i0 + wrow + q * 4;
    int labi[2][4];
    #pragma unroll
    for (int ii = 0; ii < 2; ii++) {
        int4 lv = ((const int4*)labels)[(ibase + ii * 16) >> 2];
        labi[ii][0] = lv.x; labi[ii][1] = lv.y; labi[ii][2] = lv.z; labi[ii][3] = lv.w;
    }
    float bs[2][4] = {}, ps[2][4] = {};

    int j0 = jstrip * 2048;
    int cs = tid, rs = cs >> 4, chs = cs & 15;      // this thread's staging slot
    uint4 pre[8];
    #pragma unroll
    for (int s = 0; s < 8; s++)
        pre[s] = fv[(size_t)(j0 + rs + s * 16) * 16 + chs];

    for (int t = 0; t < 16; t++) {
        __syncthreads();               // previous tile's readers done
        #pragma unroll
        for (int s = 0; s < 8; s++) {
            int r = rs + s * 16;
            sB[r * 16 + (chs ^ (r & 7))] = pre[s];
        }
        __syncthreads();
        if (t < 15) {
            int jn = j0 + (t + 1) * 128;
            #pragma unroll
            for (int s = 0; s < 8; s++)
                pre[s] = fv[(size_t)(jn + rs + s * 16) * 16 + chs];
        }
        int jt = j0 + t * 128;

        f32x4 acc[2][4];
        #pragma unroll
        for (int ii = 0; ii < 2; ii++)
            #pragma unroll
            for (int jj = 0; jj < 4; jj++) acc[ii][jj] = (f32x4){0.f, 0.f, 0.f, 0.f};
        #pragma unroll
        for (int kk = 0; kk < 4; kk++) {
            bf16x8 bfv[4];
            #pragma unroll
            for (int jj = 0; jj < 4; jj++) {
                int r = wcol + jj * 16 + l15;
                bfv[jj] = *(const bf16x8*)&sB[r * 16 + ((kk * 4 + q) ^ (r & 7))];
            }
            #pragma unroll
            for (int ii = 0; ii < 2; ii++)
                #pragma unroll
                for (int jj = 0; jj < 4; jj++)
                    acc[ii][jj] = __builtin_amdgcn_mfma_f32_16x16x32_bf16(
                        af[ii][kk], bfv[jj], acc[ii][jj], 0, 0, 0);
        }
        int labj[4];
        #pragma unroll
        for (int jj = 0; jj < 4; jj++) labj[jj] = labels[jt + wcol + jj * 16 + l15];
        #pragma unroll
        for (int ii = 0; ii < 2; ii++)
            #pragma unroll
            for (int jj = 0; jj < 4; jj++)
                #pragma unroll
                for (int r4 = 0; r4 < 4; r4++) {
                    float a = acc[ii][jj][r4];
                    bs[ii][r4] += __expf(a * INVT);
                    ps[ii][r4] += (labj[jj] == labi[ii][r4]) ? a : 0.f;
                }
    }

    #pragma unroll
    for (int ii = 0; ii < 2; ii++)
        #pragma unroll
        for (int r4 = 0; r4 < 4; r4++) {
            float b = bs[ii][r4], p = ps[ii][r4];
            #pragma unroll
            for (int o = 8; o > 0; o >>= 1) {
                b += __shfl_xor(b, o);
                p += __shfl_xor(p, o);
            }
            if (l15 == 0) {
                atomicAdd(&bottom[ibase + ii * 16 + r4], b);
                atomicAdd(&pos[ibase + ii * 16 + r4], p);
            }
        }
}

__global__ void final_kernel(const float* __restrict__ bottom, const float* __restrict__ pos,
        const int* __restrict__ labels, const int* __restrict__ counts,
        const float* __restrict__ ce_row, const float* __restrict__ m_row,
        const float* __restrict__ diag, float* __restrict__ loss_out) {
    int tid = threadIdx.x;
    float sp = 0.f, nv = 0.f, ce = 0.f, mg = 0.f;
    for (int i = tid; i < BN; i += 256) {
        ce += ce_row[i];
        mg += m_row[i];
        float d = diag[i];
        float bot = bottom[i] - __expf(d * INVT);   // exclude j==i term
        float pv = (pos[i] - d) * INVT;             // exclude j==i, apply 1/T
        int c = counts[labels[i]] - 1;
        if (c > 0) {
            sp += pv / (float)c - logf(bot);
            nv += 1.f;
        }
    }
    #pragma unroll
    for (int o = 32; o > 0; o >>= 1) {
        sp += __shfl_xor(sp, o);
        nv += __shfl_xor(nv, o);
        ce += __shfl_xor(ce, o);
        mg += __shfl_xor(mg, o);
    }
    __shared__ float r1[4], r2[4], r3[4], r4[4];
    int w = tid >> 6, lane = tid & 63;
    if (lane == 0) { r1[w] = sp; r2[w] = nv; r3[w] = ce; r4[w] = mg; }
    __syncthreads();
    if (tid == 0) {
        float SP = r1[0] + r1[1] + r1[2] + r1[3];
        float NV = r2[0] + r2[1] + r2[2] + r2[3];
        float CE = r3[0] + r3[1] + r3[2] + r3[3];
        float MG = r4[0] + r4[1] + r4[2] + r4[3];
        float scl = -SP / fmaxf(NV, 1.f);
        loss_out[0] = 0.9f * (CE / (float)BN) + 0.1f * scl + 0.5f * (MG / (2.f * (float)BN));
    }
}

extern "C" void kernel_launch(void* const* d_in, const int* in_sizes, int n_in,
                              void* d_out, int out_size, void* d_ws, size_t ws_size,
                              hipStream_t stream) {
    const float* feat   = (const float*)d_in[0];
    const int*   labels = (const int*)d_in[1];
    const float* means  = (const float*)d_in[2];
    float* out = (float*)d_out;
    float* ws  = (float*)d_ws;

    float*  featn  = ws + F_FEATN;
    float*  meansn = ws + F_MEANSN;
    float*  xx     = ws + F_XX;
    float*  yy     = ws + F_YY;
    float*  diag   = ws + F_DIAG;
    __bf16* featb  = (__bf16*)(ws + F_FEATB);
    __bf16* meansb = (__bf16*)(ws + F_MEANSB);
    float*  ce_row = ws + F_CEROW;
    float*  m_row  = ws + F_MROW;
    float*  pm     = ws + F_PM;
    float*  pl     = ws + F_PL;
    float*  plab   = ws + F_PLAB;
    float*  bottom = ws + F_BOT;
    float*  pos    = ws + F_POS;
    int*    counts = (int*)(ws + F_CNT);

    hipMemsetAsync(ws + F_BOT, 0, (size_t)(8192 + 8192 + 1000) * sizeof(float), stream);

    norm_rows<<<2048, 256, 0, stream>>>(feat, featn, xx, featb, diag, BN, 0);
    norm_rows<<<250, 256, 0, stream>>>(means, meansn, yy, nullptr, nullptr, CN, 1);
    to_bf16_pad<<<512, 256, 0, stream>>>(means, meansb, CN);
    hist_kernel<<<32, 256, 0, stream>>>(labels, counts);
    nsd_kernel<<<dim3(8, 64), 256, 0, stream>>>(featb, meansb, xx, yy, labels,
                                                out, pm, pl, plab);
    ce_merge<<<32, 256, 0, stream>>>(pm, pl, plab, ce_row);
    margin_kernel<<<2048, 256, 0, stream>>>(featn, meansn, labels, m_row);
    scl_kernel<<<dim3(4, 128), 256, 0, stream>>>(featb, labels, bottom, pos);
    final_kernel<<<1, 256, 0, stream>>>(bottom, pos, labels, counts, ce_row, m_row,
                                        diag, out + (size_t)BN * CN);
}

// Round 4
// 165.508 us; speedup vs baseline: 1.2842x; 1.2842x over previous
//
#include <hip/hip_runtime.h>
#include <math.h>

#define BN 8192
#define CN 1000
#define DN 128
#define INVT (1.0f/0.3f)

typedef __bf16 bf16x8 __attribute__((ext_vector_type(8)));
typedef float  f32x4  __attribute__((ext_vector_type(4)));

// ws layout in floats
#define F_FEATN  0          // 8192*128
#define F_MEANSN 1048576    // 1000*128
#define F_XX     1176576    // 8192
#define F_YY     1184768    // 1000
#define F_DIAG   1185768    // 8192  ||bf16(f_i)||^2
#define F_FEATB  1193960    // 8192*128 bf16 = 524288 floats
#define F_MEANSB 1718248    // 1024*128 bf16
#define F_CEROW  1783784    // 8192
#define F_MROW   1791976    // 8192
#define F_POSR   1800168    // 8192
#define F_PM     1808360    // 16*8192
#define F_PL     1939432    // 16*8192
#define F_PLAB   2070504    // 16*8192
#define F_BOT    2201576    // 8192   -- zeroed region start
#define F_CNT    2209768    // 1000 ints
#define F_CSUM   2210768    // 1000*128 class sums (zeroed)

// async global->LDS, 16B per lane. LDS dest is wave-uniform base + lane*16.
__device__ __forceinline__ void async16(const void* g, void* s) {
    __builtin_amdgcn_global_load_lds(
        (const __attribute__((address_space(1))) void*)g,
        (__attribute__((address_space(3))) void*)s, 16, 0, 0);
}

// -------- row L2-normalize; also emits bf16 copy + diag = ||bf16 row||^2 --------
__global__ void norm_rows(const float* __restrict__ src, float* __restrict__ dst,
                          float* __restrict__ sq, __bf16* __restrict__ dstb,
                          float* __restrict__ diag, int nrows, int raw_sq) {
    int row = blockIdx.x * 4 + (threadIdx.x >> 6);
    if (row >= nrows) return;
    int lane = threadIdx.x & 63;
    float f0 = src[row * DN + lane];
    float f1 = src[row * DN + 64 + lane];
    float ss = f0 * f0 + f1 * f1;
    #pragma unroll
    for (int o = 32; o > 0; o >>= 1) ss += __shfl_xor(ss, o);
    float inv = 1.0f / fmaxf(sqrtf(ss), 1e-12f);
    float n0 = f0 * inv, n1 = f1 * inv;
    dst[row * DN + lane] = n0;
    dst[row * DN + 64 + lane] = n1;
    if (dstb) {
        __bf16 b0 = (__bf16)n0, b1 = (__bf16)n1;
        dstb[row * DN + lane] = b0;
        dstb[row * DN + 64 + lane] = b1;
        float fb0 = (float)b0, fb1 = (float)b1;
        float sb = fb0 * fb0 + fb1 * fb1;
        #pragma unroll
        for (int o = 32; o > 0; o >>= 1) sb += __shfl_xor(sb, o);
        if (lane == 0) diag[row] = sb;
    }
    if (lane == 0) sq[row] = raw_sq ? ss : ss * inv * inv;
}

__global__ void to_bf16_pad(const float* __restrict__ src, __bf16* __restrict__ dst,
                            int nrows_src) {
    int idx = blockIdx.x * 256 + threadIdx.x;     // 1024*128 total
    int row = idx >> 7;
    dst[idx] = (__bf16)((row < nrows_src) ? src[idx] : 0.f);
}

__global__ void hist_kernel(const int* __restrict__ labels, int* __restrict__ counts) {
    int i = blockIdx.x * 256 + threadIdx.x;
    atomicAdd(&counts[labels[i]], 1);
}

// class-sum vectors: csum[c][d] = sum over rows with label c of featn[row][d]
__global__ void csum_kernel(const float* __restrict__ featn, const int* __restrict__ labels,
                            float* __restrict__ csum) {
    int idx = blockIdx.x * 256 + threadIdx.x;    // 8192*128
    int row = idx >> 7, d = idx & 127;
    atomicAdd(&csum[labels[row] * DN + d], featn[idx]);
}

// stage a 128x128 bf16 tile into LDS as XOR-swizzled 16B chunks (reg round-trip; used by nsd)
__device__ __forceinline__ void stage128(uint4* sT, const uint4* __restrict__ src,
                                         int row0, int tid) {
    #pragma unroll
    for (int s = 0; s < 8; s++) {
        int c = tid + s * 256;
        int r = c >> 4, ch = c & 15;
        sT[r * 16 + (ch ^ (r & 7))] = src[(size_t)(row0 + r) * 16 + ch];
    }
}

// -------- nsd + fused CE partials (validated in round 3) --------
__global__ __launch_bounds__(256, 2) void nsd_kernel(const __bf16* __restrict__ featb,
        const __bf16* __restrict__ meansb, const float* __restrict__ xx,
        const float* __restrict__ yy, const int* __restrict__ labels,
        float* __restrict__ out, float* __restrict__ pm, float* __restrict__ pl,
        float* __restrict__ plab) {
    __shared__ uint4 sA[2048];
    __shared__ uint4 sB[2048];
    int tid = threadIdx.x;
    int i0 = blockIdx.y * 128, j0 = blockIdx.x * 128;
    stage128(sA, (const uint4*)featb, i0, tid);
    stage128(sB, (const uint4*)meansb, j0, tid);
    __syncthreads();
    int lane = tid & 63, w = tid >> 6;
    int wrow = (w >> 1) * 64, wcol = (w & 1) * 64;
    int q = lane >> 4, l15 = lane & 15;
    int ibase = i0 + wrow + q * 4;

    f32x4 acc[4][4];
    #pragma unroll
    for (int ii = 0; ii < 4; ii++)
        #pragma unroll
        for (int jj = 0; jj < 4; jj++) acc[ii][jj] = (f32x4){0.f, 0.f, 0.f, 0.f};
    #pragma unroll
    for (int kk = 0; kk < 4; kk++) {
        bf16x8 af[4], bfv[4];
        #pragma unroll
        for (int ii = 0; ii < 4; ii++) {
            int r = wrow + ii * 16 + l15;
            af[ii] = *(const bf16x8*)&sA[r * 16 + ((kk * 4 + q) ^ (r & 7))];
        }
        #pragma unroll
        for (int jj = 0; jj < 4; jj++) {
            int r = wcol + jj * 16 + l15;
            bfv[jj] = *(const bf16x8*)&sB[r * 16 + ((kk * 4 + q) ^ (r & 7))];
        }
        #pragma unroll
        for (int ii = 0; ii < 4; ii++)
            #pragma unroll
            for (int jj = 0; jj < 4; jj++)
                acc[ii][jj] = __builtin_amdgcn_mfma_f32_16x16x32_bf16(
                    af[ii], bfv[jj], acc[ii][jj], 0, 0, 0);
    }
    int jg[4]; float yv[4];
    #pragma unroll
    for (int jj = 0; jj < 4; jj++) {
        jg[jj] = j0 + wcol + jj * 16 + l15;
        yv[jj] = (jg[jj] < CN) ? yy[jg[jj]] : 0.f;
    }
    int pslot = (blockIdx.x * 2 + (w & 1)) * BN;
    #pragma unroll
    for (int ii = 0; ii < 4; ii++) {
        int rbase = ibase + ii * 16;
        float4 xv = ((const float4*)xx)[rbase >> 2];
        int4 lv = ((const int4*)labels)[rbase >> 2];
        float xa[4] = {xv.x, xv.y, xv.z, xv.w};
        int la[4] = {lv.x, lv.y, lv.z, lv.w};
        #pragma unroll
        for (int r4 = 0; r4 < 4; r4++) {
            int ig = rbase + r4;
            float m = -INFINITY, labc = -INFINITY;
            float lgt[4];
            #pragma unroll
            for (int jj = 0; jj < 4; jj++) {
                float v = -0.5f * (xa[r4] - 2.f * acc[ii][jj][r4] + yv[jj]);
                bool ok = (jg[jj] < CN);
                if (ok) out[(size_t)ig * CN + jg[jj]] = v;
                bool isl = ok && (jg[jj] == la[r4]);
                float l = isl ? 1.5f * v : v;
                if (!ok) l = -INFINITY;
                lgt[jj] = l;
                m = fmaxf(m, l);
                labc = isl ? l : labc;
            }
            float s = 0.f;
            #pragma unroll
            for (int jj = 0; jj < 4; jj++) s += __expf(lgt[jj] - m);
            #pragma unroll
            for (int o = 8; o > 0; o >>= 1) {
                float mo = __shfl_xor(m, o), so = __shfl_xor(s, o);
                float M = fmaxf(m, mo);
                s = s * __expf(m - M) + so * __expf(mo - M);
                m = M;
                labc = fmaxf(labc, __shfl_xor(labc, o));
            }
            if (l15 == 0) {
                pm[pslot + ig] = m;
                pl[pslot + ig] = s;
                plab[pslot + ig] = labc;
            }
        }
    }
}

__global__ void ce_merge(const float* __restrict__ pm, const float* __restrict__ pl,
                         const float* __restrict__ plab, float* __restrict__ ce_row) {
    int row = blockIdx.x * 256 + threadIdx.x;
    float M = -INFINITY;
    #pragma unroll
    for (int k = 0; k < 16; k++) M = fmaxf(M, pm[k * BN + row]);
    float S = 0.f; float lv = -INFINITY;
    #pragma unroll
    for (int k = 0; k < 16; k++) {
        S += pl[k * BN + row] * __expf(pm[k * BN + row] - M);
        lv = fmaxf(lv, plab[k * BN + row]);
    }
    ce_row[row] = (M + logf(S)) - lv;
}

// margin + pos per row: m_row = ||f - mean_lab||^2 ; pos_row = f . csum[lab] (incl. self)
__global__ void margin_pos_kernel(const float* __restrict__ featn,
        const float* __restrict__ meansn, const float* __restrict__ csum,
        const int* __restrict__ labels, float* __restrict__ m_row,
        float* __restrict__ pos_row) {
    int row = blockIdx.x * 4 + (threadIdx.x >> 6);
    int lane = threadIdx.x & 63;
    int lab = labels[row];
    float f0 = featn[row * DN + lane],        f1 = featn[row * DN + 64 + lane];
    float m0 = meansn[lab * DN + lane],       m1 = meansn[lab * DN + 64 + lane];
    float c0 = csum[lab * DN + lane],         c1 = csum[lab * DN + 64 + lane];
    float d0 = f0 - m0, d1 = f1 - m1;
    float ss = d0 * d0 + d1 * d1;
    float pp = f0 * c0 + f1 * c1;
    #pragma unroll
    for (int o = 32; o > 0; o >>= 1) {
        ss += __shfl_xor(ss, o);
        pp += __shfl_xor(pp, o);
    }
    if (lane == 0) { m_row[row] = ss; pos_row[row] = pp; }
}

// -------- SCL core: 128x128 i-tile x 8 j-tiles. A-frags in registers (global),
// B double-buffered in LDS via async global_load_lds (swizzle folded into the
// per-lane SOURCE address), raw s_barrier + manual vmcnt so prefetch stays in
// flight across barriers. Epilogue: bottom only (pos computed analytically). --------
__global__ __launch_bounds__(256, 2) void scl_kernel(const __bf16* __restrict__ featb,
        float* __restrict__ bottom) {
    __shared__ uint4 sB[2][2048];
    int tid = threadIdx.x;
    int lane = tid & 63, w = tid >> 6;
    int q = lane >> 4, l15 = lane & 15;
    int i0 = blockIdx.y * 128;
    int j0s = blockIdx.x * 1024;          // strip of 8 tiles
    const uint4* fv = (const uint4*)featb;
    int wrow = (w >> 1) * 64, wcol = (w & 1) * 64;

    // A fragments straight from global (featb is L2-resident, 2 MB)
    bf16x8 af[4][4];
    #pragma unroll
    for (int ii = 0; ii < 4; ii++) {
        size_t r = (size_t)(i0 + wrow + ii * 16 + l15) * 16;
        #pragma unroll
        for (int kk = 0; kk < 4; kk++)
            af[ii][kk] = *(const bf16x8*)&fv[r + kk * 4 + q];
    }
    float bs[4][4] = {};

    // stage one 128x128 tile (32 KB): each wave issues 8 async 1KB copies.
    // LDS slot (row r, chunk sl) receives source chunk sl^(r&7)  (XOR swizzle via source).
    auto stage = [&](int tj0, int buf) {
        #pragma unroll
        for (int s = 0; s < 8; s++) {
            int rb = w * 32 + s * 4;             // wave-uniform 4-row group
            int r = rb + q;                      // this lane's row
            async16(&fv[(size_t)(tj0 + r) * 16 + (l15 ^ (r & 7))], &sB[buf][rb * 16]);
        }
    };

    stage(j0s, 0);
    stage(j0s + 128, 1);

    for (int t = 0; t < 8; t++) {
        // wait for tile t's 8 DMAs (t+1's 8 may stay in flight)
        if (t < 7) asm volatile("s_waitcnt vmcnt(8)" ::: "memory");
        else       asm volatile("s_waitcnt vmcnt(0)" ::: "memory");
        __builtin_amdgcn_s_barrier();
        const uint4* B = sB[t & 1];

        f32x4 acc[4][4];
        #pragma unroll
        for (int ii = 0; ii < 4; ii++)
            #pragma unroll
            for (int jj = 0; jj < 4; jj++) acc[ii][jj] = (f32x4){0.f, 0.f, 0.f, 0.f};
        #pragma unroll
        for (int kk = 0; kk < 4; kk++) {
            bf16x8 bfv[4];
            #pragma unroll
            for (int jj = 0; jj < 4; jj++) {
                int r = wcol + jj * 16 + l15;
                bfv[jj] = *(const bf16x8*)&B[r * 16 + ((kk * 4 + q) ^ (r & 7))];
            }
            #pragma unroll
            for (int ii = 0; ii < 4; ii++)
                #pragma unroll
                for (int jj = 0; jj < 4; jj++)
                    acc[ii][jj] = __builtin_amdgcn_mfma_f32_16x16x32_bf16(
                        af[ii][kk], bfv[jj], acc[ii][jj], 0, 0, 0);
        }
        #pragma unroll
        for (int ii = 0; ii < 4; ii++)
            #pragma unroll
            for (int jj = 0; jj < 4; jj++)
                #pragma unroll
                for (int r4 = 0; r4 < 4; r4++)
                    bs[ii][r4] += __expf(acc[ii][jj][r4] * INVT);
        __builtin_amdgcn_s_barrier();          // everyone done reading buf[t&1]
        if (t < 6) stage(j0s + (t + 2) * 128, t & 1);
    }

    int ibase = i0 + wrow + q * 4;
    #pragma unroll
    for (int ii = 0; ii < 4; ii++)
        #pragma unroll
        for (int r4 = 0; r4 < 4; r4++) {
            float b = bs[ii][r4];
            #pragma unroll
            for (int o = 8; o > 0; o >>= 1) b += __shfl_xor(b, o);
            if (l15 == 0) atomicAdd(&bottom[ibase + ii * 16 + r4], b);
        }
}

__global__ void final_kernel(const float* __restrict__ bottom, const float* __restrict__ pos_row,
        const int* __restrict__ labels, const int* __restrict__ counts,
        const float* __restrict__ ce_row, const float* __restrict__ m_row,
        const float* __restrict__ diag, const float* __restrict__ xx,
        float* __restrict__ loss_out) {
    int tid = threadIdx.x;
    float sp = 0.f, nv = 0.f, ce = 0.f, mg = 0.f;
    for (int i = tid; i < BN; i += 256) {
        ce += ce_row[i];
        mg += m_row[i];
        float bot = bottom[i] - __expf(diag[i] * INVT);   // exclude j==i (bf16 diag)
        float pv = (pos_row[i] - xx[i]) * INVT;           // exclude j==i (fp32), apply 1/T
        int c = counts[labels[i]] - 1;
        if (c > 0) {
            sp += pv / (float)c - logf(bot);
            nv += 1.f;
        }
    }
    #pragma unroll
    for (int o = 32; o > 0; o >>= 1) {
        sp += __shfl_xor(sp, o);
        nv += __shfl_xor(nv, o);
        ce += __shfl_xor(ce, o);
        mg += __shfl_xor(mg, o);
    }
    __shared__ float r1[4], r2[4], r3[4], r4[4];
    int w = tid >> 6, lane = tid & 63;
    if (lane == 0) { r1[w] = sp; r2[w] = nv; r3[w] = ce; r4[w] = mg; }
    __syncthreads();
    if (tid == 0) {
        float SP = r1[0] + r1[1] + r1[2] + r1[3];
        float NV = r2[0] + r2[1] + r2[2] + r2[3];
        float CE = r3[0] + r3[1] + r3[2] + r3[3];
        float MG = r4[0] + r4[1] + r4[2] + r4[3];
        float scl = -SP / fmaxf(NV, 1.f);
        loss_out[0] = 0.9f * (CE / (float)BN) + 0.1f * scl + 0.5f * (MG / (2.f * (float)BN));
    }
}

extern "C" void kernel_launch(void* const* d_in, const int* in_sizes, int n_in,
                              void* d_out, int out_size, void* d_ws, size_t ws_size,
                              hipStream_t stream) {
    const float* feat   = (const float*)d_in[0];
    const int*   labels = (const int*)d_in[1];
    const float* means  = (const float*)d_in[2];
    float* out = (float*)d_out;
    float* ws  = (float*)d_ws;

    float*  featn  = ws + F_FEATN;
    float*  meansn = ws + F_MEANSN;
    float*  xx     = ws + F_XX;
    float*  yy     = ws + F_YY;
    float*  diag   = ws + F_DIAG;
    __bf16* featb  = (__bf16*)(ws + F_FEATB);
    __bf16* meansb = (__bf16*)(ws + F_MEANSB);
    float*  ce_row = ws + F_CEROW;
    float*  m_row  = ws + F_MROW;
    float*  posr   = ws + F_POSR;
    float*  pm     = ws + F_PM;
    float*  pl     = ws + F_PL;
    float*  plab   = ws + F_PLAB;
    float*  bottom = ws + F_BOT;
    int*    counts = (int*)(ws + F_CNT);
    float*  csum   = ws + F_CSUM;

    // zero bottom + counts + csum (contiguous)
    hipMemsetAsync(ws + F_BOT, 0, (size_t)(8192 + 1000 + 128000) * sizeof(float), stream);

    norm_rows<<<2048, 256, 0, stream>>>(feat, featn, xx, featb, diag, BN, 0);
    norm_rows<<<250, 256, 0, stream>>>(means, meansn, yy, nullptr, nullptr, CN, 1);
    to_bf16_pad<<<512, 256, 0, stream>>>(means, meansb, CN);
    hist_kernel<<<32, 256, 0, stream>>>(labels, counts);
    csum_kernel<<<4096, 256, 0, stream>>>(featn, labels, csum);
    nsd_kernel<<<dim3(8, 64), 256, 0, stream>>>(featb, meansb, xx, yy, labels,
                                                out, pm, pl, plab);
    ce_merge<<<32, 256, 0, stream>>>(pm, pl, plab, ce_row);
    margin_pos_kernel<<<2048, 256, 0, stream>>>(featn, meansn, csum, labels, m_row, posr);
    scl_kernel<<<dim3(8, 64), 256, 0, stream>>>(featb, bottom);
    final_kernel<<<1, 256, 0, stream>>>(bottom, posr, labels, counts, ce_row, m_row,
                                        diag, xx, out + (size_t)BN * CN);
}

// Round 5
// 154.694 us; speedup vs baseline: 1.3740x; 1.0699x over previous
//
#include <hip/hip_runtime.h>
#include <math.h>

#define BN 8192
#define CN 1000
#define DN 128
#define INVT (1.0f/0.3f)
#define EXP2C 4.80898346962988f   // (1/0.3) * log2(e)

typedef __bf16 bf16x8 __attribute__((ext_vector_type(8)));
typedef float  f32x4  __attribute__((ext_vector_type(4)));

// ws layout in floats
#define F_FEATN  0          // 8192*128
#define F_MEANSN 1048576    // 1000*128
#define F_XX     1176576    // 8192
#define F_YY     1184768    // 1000
#define F_DIAG   1185768    // 8192  ||bf16(f_i)||^2
#define F_FEATB  1193960    // 8192*128 bf16 = 524288 floats
#define F_MEANSB 1718248    // 1024*128 bf16
#define F_CEROW  1783784    // 8192
#define F_MROW   1791976    // 8192
#define F_POSR   1800168    // 8192
#define F_PM     1808360    // 16*8192
#define F_PL     1939432    // 16*8192
#define F_PLAB   2070504    // 16*8192
#define F_BOT    2201576    // 8192   -- zeroed region start
#define F_CNT    2209768    // 1000 ints
#define F_CSUM   2210768    // 1000*128 class sums (zeroed)

// mega-kernel block ranges
#define NB_SCL  544          // triangular strips of <=4 tiles
#define NB_NSD  512          // 8 x 64 nsd tiles
#define NB_CSUM 512

__device__ __forceinline__ void async16(const void* g, void* s) {
    __builtin_amdgcn_global_load_lds(
        (const __attribute__((address_space(1))) void*)g,
        (__attribute__((address_space(3))) void*)s, 16, 0, 0);
}

// -------- feat: L2-normalize + bf16 copy + diag + label histogram --------
__global__ void norm_feat(const float* __restrict__ src, float* __restrict__ dst,
                          float* __restrict__ sq, __bf16* __restrict__ dstb,
                          float* __restrict__ diag, const int* __restrict__ labels,
                          int* __restrict__ counts) {
    int row = blockIdx.x * 4 + (threadIdx.x >> 6);
    int lane = threadIdx.x & 63;
    float f0 = src[row * DN + lane];
    float f1 = src[row * DN + 64 + lane];
    float ss = f0 * f0 + f1 * f1;
    #pragma unroll
    for (int o = 32; o > 0; o >>= 1) ss += __shfl_xor(ss, o);
    float inv = 1.0f / fmaxf(sqrtf(ss), 1e-12f);
    float n0 = f0 * inv, n1 = f1 * inv;
    dst[row * DN + lane] = n0;
    dst[row * DN + 64 + lane] = n1;
    __bf16 b0 = (__bf16)n0, b1 = (__bf16)n1;
    dstb[row * DN + lane] = b0;
    dstb[row * DN + 64 + lane] = b1;
    float fb0 = (float)b0, fb1 = (float)b1;
    float sb = fb0 * fb0 + fb1 * fb1;
    #pragma unroll
    for (int o = 32; o > 0; o >>= 1) sb += __shfl_xor(sb, o);
    if (lane == 0) {
        diag[row] = sb;
        sq[row] = ss * inv * inv;
        atomicAdd(&counts[labels[row]], 1);
    }
}

// -------- means: normalize (fp32) + yy + raw-bf16 copy padded to 1024 rows --------
__global__ void norm_means(const float* __restrict__ src, float* __restrict__ dst,
                           float* __restrict__ sq, __bf16* __restrict__ dstb) {
    int row = blockIdx.x * 4 + (threadIdx.x >> 6);   // 0..1023
    int lane = threadIdx.x & 63;
    float f0 = (row < CN) ? src[row * DN + lane] : 0.f;
    float f1 = (row < CN) ? src[row * DN + 64 + lane] : 0.f;
    dstb[row * DN + lane] = (__bf16)f0;
    dstb[row * DN + 64 + lane] = (__bf16)f1;
    if (row >= CN) return;
    float ss = f0 * f0 + f1 * f1;
    #pragma unroll
    for (int o = 32; o > 0; o >>= 1) ss += __shfl_xor(ss, o);
    float inv = 1.0f / fmaxf(sqrtf(ss), 1e-12f);
    dst[row * DN + lane] = f0 * inv;
    dst[row * DN + 64 + lane] = f1 * inv;
    if (lane == 0) sq[row] = ss;
}

// stage a 128x128 bf16 tile into LDS, XOR-swizzled (register round-trip; nsd path)
__device__ __forceinline__ void stage128(uint4* sT, const uint4* __restrict__ src,
                                         int row0, int tid) {
    #pragma unroll
    for (int s = 0; s < 8; s++) {
        int c = tid + s * 256;
        int r = c >> 4, ch = c & 15;
        sT[r * 16 + (ch ^ (r & 7))] = src[(size_t)(row0 + r) * 16 + ch];
    }
}

// -------- mega kernel: [0,544) scl triangular strips | [544,1056) nsd | [1056,1568) csum --------
__global__ __launch_bounds__(256, 2) void mega_kernel(
        const __bf16* __restrict__ featb, const __bf16* __restrict__ meansb,
        const float* __restrict__ featn, const int* __restrict__ labels,
        const float* __restrict__ xx, const float* __restrict__ yy,
        float* __restrict__ out, float* __restrict__ pm, float* __restrict__ pl,
        float* __restrict__ plab, float* __restrict__ bottom, float* __restrict__ csum) {
    __shared__ uint4 sh[2][2048];
    int bx = blockIdx.x;
    int tid = threadIdx.x;
    int lane = tid & 63, w = tid >> 6;
    int q = lane >> 4, l15 = lane & 15;

    if (bx < NB_SCL) {
        // ---- SCL: triangular strip of <=4 tiles at row-block I, cols J0.. ----
        int rem = bx, I = 0;
        while (true) { int ns = (64 - I + 3) >> 2; if (rem < ns) break; rem -= ns; ++I; }
        int J0 = I + rem * 4;
        int len = min(4, 64 - J0);
        int i0 = I * 128;
        const uint4* fv = (const uint4*)featb;
        int wrow = (w >> 1) * 64, wcol = (w & 1) * 64;

        bf16x8 af[4][4];
        #pragma unroll
        for (int ii = 0; ii < 4; ii++) {
            size_t r = (size_t)(i0 + wrow + ii * 16 + l15) * 16;
            #pragma unroll
            for (int kk = 0; kk < 4; kk++)
                af[ii][kk] = *(const bf16x8*)&fv[r + kk * 4 + q];
        }
        float bs[4][4] = {};

        auto stage = [&](int row0, int buf) {
            #pragma unroll
            for (int s = 0; s < 8; s++) {
                int rb = w * 32 + s * 4;
                int r = rb + q;
                async16(&fv[(size_t)(row0 + r) * 16 + (l15 ^ (r & 7))], &sh[buf][rb * 16]);
            }
        };

        stage(J0 * 128, 0);
        if (len > 1) stage(J0 * 128 + 128, 1);

        for (int t = 0; t < len; t++) {
            if (t + 1 < len) asm volatile("s_waitcnt vmcnt(8)" ::: "memory");
            else             asm volatile("s_waitcnt vmcnt(0)" ::: "memory");
            __builtin_amdgcn_s_barrier();
            const uint4* B = sh[t & 1];

            f32x4 acc[4][4];
            #pragma unroll
            for (int ii = 0; ii < 4; ii++)
                #pragma unroll
                for (int jj = 0; jj < 4; jj++) acc[ii][jj] = (f32x4){0.f, 0.f, 0.f, 0.f};
            #pragma unroll
            for (int kk = 0; kk < 4; kk++) {
                bf16x8 bfv[4];
                #pragma unroll
                for (int jj = 0; jj < 4; jj++) {
                    int r = wcol + jj * 16 + l15;
                    bfv[jj] = *(const bf16x8*)&B[r * 16 + ((kk * 4 + q) ^ (r & 7))];
                }
                #pragma unroll
                for (int ii = 0; ii < 4; ii++)
                    #pragma unroll
                    for (int jj = 0; jj < 4; jj++)
                        acc[ii][jj] = __builtin_amdgcn_mfma_f32_16x16x32_bf16(
                            af[ii][kk], bfv[jj], acc[ii][jj], 0, 0, 0);
            }

            int jt = (J0 + t) * 128;
            float cp[4] = {0.f, 0.f, 0.f, 0.f};
            #pragma unroll
            for (int ii = 0; ii < 4; ii++)
                #pragma unroll
                for (int jj = 0; jj < 4; jj++)
                    #pragma unroll
                    for (int r4 = 0; r4 < 4; r4++) {
                        float e = exp2f(acc[ii][jj][r4] * EXP2C);
                        bs[ii][r4] += e;
                        cp[jj] += e;
                    }
            if (J0 + t != I) {      // off-diagonal: mirror contribution to bottom[j]
                #pragma unroll
                for (int jj = 0; jj < 4; jj++) {
                    float c = cp[jj];
                    c += __shfl_xor(c, 16);
                    c += __shfl_xor(c, 32);
                    if (lane < 16)
                        atomicAdd(&bottom[jt + wcol + jj * 16 + l15], c);
                }
            }
            __builtin_amdgcn_s_barrier();
            if (t + 2 < len) stage((J0 + t + 2) * 128, t & 1);
        }

        int ibase = i0 + wrow + q * 4;
        #pragma unroll
        for (int ii = 0; ii < 4; ii++)
            #pragma unroll
            for (int r4 = 0; r4 < 4; r4++) {
                float b = bs[ii][r4];
                #pragma unroll
                for (int o = 8; o > 0; o >>= 1) b += __shfl_xor(b, o);
                if (l15 == 0) atomicAdd(&bottom[ibase + ii * 16 + r4], b);
            }

    } else if (bx < NB_SCL + NB_NSD) {
        // ---- NSD + fused CE partials (validated round 3/4) ----
        int b = bx - NB_SCL;
        int i0 = (b >> 3) * 128, j0 = (b & 7) * 128;
        stage128(sh[0], (const uint4*)featb, i0, tid);
        stage128(sh[1], (const uint4*)meansb, j0, tid);
        __syncthreads();
        int wrow = (w >> 1) * 64, wcol = (w & 1) * 64;
        int ibase = i0 + wrow + q * 4;

        f32x4 acc[4][4];
        #pragma unroll
        for (int ii = 0; ii < 4; ii++)
            #pragma unroll
            for (int jj = 0; jj < 4; jj++) acc[ii][jj] = (f32x4){0.f, 0.f, 0.f, 0.f};
        #pragma unroll
        for (int kk = 0; kk < 4; kk++) {
            bf16x8 af[4], bfv[4];
            #pragma unroll
            for (int ii = 0; ii < 4; ii++) {
                int r = wrow + ii * 16 + l15;
                af[ii] = *(const bf16x8*)&sh[0][r * 16 + ((kk * 4 + q) ^ (r & 7))];
            }
            #pragma unroll
            for (int jj = 0; jj < 4; jj++) {
                int r = wcol + jj * 16 + l15;
                bfv[jj] = *(const bf16x8*)&sh[1][r * 16 + ((kk * 4 + q) ^ (r & 7))];
            }
            #pragma unroll
            for (int ii = 0; ii < 4; ii++)
                #pragma unroll
                for (int jj = 0; jj < 4; jj++)
                    acc[ii][jj] = __builtin_amdgcn_mfma_f32_16x16x32_bf16(
                        af[ii], bfv[jj], acc[ii][jj], 0, 0, 0);
        }
        int jg[4]; float yv[4];
        #pragma unroll
        for (int jj = 0; jj < 4; jj++) {
            jg[jj] = j0 + wcol + jj * 16 + l15;
            yv[jj] = (jg[jj] < CN) ? yy[jg[jj]] : 0.f;
        }
        int pslot = ((b & 7) * 2 + (w & 1)) * BN;
        #pragma unroll
        for (int ii = 0; ii < 4; ii++) {
            int rbase = ibase + ii * 16;
            float4 xv = ((const float4*)xx)[rbase >> 2];
            int4 lv = ((const int4*)labels)[rbase >> 2];
            float xa[4] = {xv.x, xv.y, xv.z, xv.w};
            int la[4] = {lv.x, lv.y, lv.z, lv.w};
            #pragma unroll
            for (int r4 = 0; r4 < 4; r4++) {
                int ig = rbase + r4;
                float m = -INFINITY, labc = -INFINITY;
                float lgt[4];
                #pragma unroll
                for (int jj = 0; jj < 4; jj++) {
                    float v = -0.5f * (xa[r4] - 2.f * acc[ii][jj][r4] + yv[jj]);
                    bool ok = (jg[jj] < CN);
                    if (ok) out[(size_t)ig * CN + jg[jj]] = v;
                    bool isl = ok && (jg[jj] == la[r4]);
                    float l = isl ? 1.5f * v : v;
                    if (!ok) l = -INFINITY;
                    lgt[jj] = l;
                    m = fmaxf(m, l);
                    labc = isl ? l : labc;
                }
                float s = 0.f;
                #pragma unroll
                for (int jj = 0; jj < 4; jj++) s += __expf(lgt[jj] - m);
                #pragma unroll
                for (int o = 8; o > 0; o >>= 1) {
                    float mo = __shfl_xor(m, o), so = __shfl_xor(s, o);
                    float M = fmaxf(m, mo);
                    s = s * __expf(m - M) + so * __expf(mo - M);
                    m = M;
                    labc = fmaxf(labc, __shfl_xor(labc, o));
                }
                if (l15 == 0) {
                    pm[pslot + ig] = m;
                    pl[pslot + ig] = s;
                    plab[pslot + ig] = labc;
                }
            }
        }

    } else {
        // ---- csum: class-sum vectors via atomics ----
        int b2 = bx - NB_SCL - NB_NSD;
        for (int idx = b2 * 256 + tid; idx < BN * DN; idx += NB_CSUM * 256) {
            int row = idx >> 7, d = idx & 127;
            atomicAdd(&csum[labels[row] * DN + d], featn[idx]);
        }
    }
}

// -------- fused: margin + pos dots (all lanes) + ce partial merge (lanes 0-15) --------
__global__ void cemp_kernel(const float* __restrict__ featn, const float* __restrict__ meansn,
        const float* __restrict__ csum, const int* __restrict__ labels,
        const float* __restrict__ pm, const float* __restrict__ pl,
        const float* __restrict__ plab, float* __restrict__ m_row,
        float* __restrict__ pos_row, float* __restrict__ ce_row) {
    int row = blockIdx.x * 4 + (threadIdx.x >> 6);
    int lane = threadIdx.x & 63;
    int lab = labels[row];
    float f0 = featn[row * DN + lane],  f1 = featn[row * DN + 64 + lane];
    float m0 = meansn[lab * DN + lane], m1 = meansn[lab * DN + 64 + lane];
    float c0 = csum[lab * DN + lane],   c1 = csum[lab * DN + 64 + lane];
    float d0 = f0 - m0, d1 = f1 - m1;
    float ss = d0 * d0 + d1 * d1;
    float pp = f0 * c0 + f1 * c1;
    #pragma unroll
    for (int o = 32; o > 0; o >>= 1) {
        ss += __shfl_xor(ss, o);
        pp += __shfl_xor(pp, o);
    }
    if (lane == 0) { m_row[row] = ss; pos_row[row] = pp; }

    // ce merge over 16 partials, handled by lanes 0..15 (shuffles stay in 16-lane groups)
    float pmv = -INFINITY;
    if (lane < 16) pmv = pm[lane * BN + row];
    float mk = pmv;
    #pragma unroll
    for (int o = 8; o > 0; o >>= 1) mk = fmaxf(mk, __shfl_xor(mk, o));
    float sk = 0.f, lk = -INFINITY;
    if (lane < 16) {
        sk = pl[lane * BN + row] * __expf(pmv - mk);
        lk = plab[lane * BN + row];
    }
    #pragma unroll
    for (int o = 8; o > 0; o >>= 1) {
        sk += __shfl_xor(sk, o);
        lk = fmaxf(lk, __shfl_xor(lk, o));
    }
    if (lane == 0) ce_row[row] = (mk + logf(sk)) - lk;
}

__global__ void final_kernel(const float* __restrict__ bottom, const float* __restrict__ pos_row,
        const int* __restrict__ labels, const int* __restrict__ counts,
        const float* __restrict__ ce_row, const float* __restrict__ m_row,
        const float* __restrict__ diag, const float* __restrict__ xx,
        float* __restrict__ loss_out) {
    int tid = threadIdx.x;
    float sp = 0.f, nv = 0.f, ce = 0.f, mg = 0.f;
    for (int i = tid; i < BN; i += 256) {
        ce += ce_row[i];
        mg += m_row[i];
        float bot = bottom[i] - __expf(diag[i] * INVT);   // exclude j==i (bf16 diag)
        float pv = (pos_row[i] - xx[i]) * INVT;           // exclude j==i (fp32), apply 1/T
        int c = counts[labels[i]] - 1;
        if (c > 0) {
            sp += pv / (float)c - logf(bot);
            nv += 1.f;
        }
    }
    #pragma unroll
    for (int o = 32; o > 0; o >>= 1) {
        sp += __shfl_xor(sp, o);
        nv += __shfl_xor(nv, o);
        ce += __shfl_xor(ce, o);
        mg += __shfl_xor(mg, o);
    }
    __shared__ float r1[4], r2[4], r3[4], r4[4];
    int w = tid >> 6, lane = tid & 63;
    if (lane == 0) { r1[w] = sp; r2[w] = nv; r3[w] = ce; r4[w] = mg; }
    __syncthreads();
    if (tid == 0) {
        float SP = r1[0] + r1[1] + r1[2] + r1[3];
        float NV = r2[0] + r2[1] + r2[2] + r2[3];
        float CE = r3[0] + r3[1] + r3[2] + r3[3];
        float MG = r4[0] + r4[1] + r4[2] + r4[3];
        float scl = -SP / fmaxf(NV, 1.f);
        loss_out[0] = 0.9f * (CE / (float)BN) + 0.1f * scl + 0.5f * (MG / (2.f * (float)BN));
    }
}

extern "C" void kernel_launch(void* const* d_in, const int* in_sizes, int n_in,
                              void* d_out, int out_size, void* d_ws, size_t ws_size,
                              hipStream_t stream) {
    const float* feat   = (const float*)d_in[0];
    const int*   labels = (const int*)d_in[1];
    const float* means  = (const float*)d_in[2];
    float* out = (float*)d_out;
    float* ws  = (float*)d_ws;

    float*  featn  = ws + F_FEATN;
    float*  meansn = ws + F_MEANSN;
    float*  xx     = ws + F_XX;
    float*  yy     = ws + F_YY;
    float*  diag   = ws + F_DIAG;
    __bf16* featb  = (__bf16*)(ws + F_FEATB);
    __bf16* meansb = (__bf16*)(ws + F_MEANSB);
    float*  ce_row = ws + F_CEROW;
    float*  m_row  = ws + F_MROW;
    float*  posr   = ws + F_POSR;
    float*  pm     = ws + F_PM;
    float*  pl     = ws + F_PL;
    float*  plab   = ws + F_PLAB;
    float*  bottom = ws + F_BOT;
    int*    counts = (int*)(ws + F_CNT);
    float*  csum   = ws + F_CSUM;

    // zero bottom + counts + csum (contiguous)
    hipMemsetAsync(ws + F_BOT, 0, (size_t)(8192 + 1000 + 128000) * sizeof(float), stream);

    norm_feat<<<2048, 256, 0, stream>>>(feat, featn, xx, featb, diag, labels, counts);
    norm_means<<<256, 256, 0, stream>>>(means, meansn, yy, meansb);
    mega_kernel<<<NB_SCL + NB_NSD + NB_CSUM, 256, 0, stream>>>(
        featb, meansb, featn, labels, xx, yy, out, pm, pl, plab, bottom, csum);
    cemp_kernel<<<2048, 256, 0, stream>>>(featn, meansn, csum, labels, pm, pl, plab,
                                          m_row, posr, ce_row);
    final_kernel<<<1, 256, 0, stream>>>(bottom, posr, labels, counts, ce_row, m_row,
                                        diag, xx, out + (size_t)BN * CN);
}